// Round 11
// baseline (308.235 us; speedup 1.0000x reference)
//
#include <hip/hip_runtime.h>
#include <math.h>

// Problem constants
#define NL    1568          // left nodes (B*P)
#define NTOT  3136          // total nodes
#define DD    768           // feature dim
#define NH    12            // heads
#define DHD   64            // head dim
#define WPR   49            // mask words per row (1568/32)
#define MAXDEG 64           // neighbor-list capacity
#define NKSTEP 24           // 768 / 32
#define LOG2F_ 0.69314718055994530942f

typedef _Float16 h8 __attribute__((ext_vector_type(8)));
typedef float f32x4 __attribute__((ext_vector_type(4)));
typedef float f32x16 __attribute__((ext_vector_type(16)));
#define MFMA16(a, b, c) __builtin_amdgcn_mfma_f32_16x16x32_f16(a, b, c, 0, 0, 0)
#define MFMA32(a, b, c) __builtin_amdgcn_mfma_f32_32x32x16_f16(a, b, c, 0, 0, 0)

__device__ __forceinline__ float leaky(float x) { return x > 0.f ? x : 0.2f * x; }

__device__ __forceinline__ void gld16(const _Float16* g, _Float16* l) {
  __builtin_amdgcn_global_load_lds(
      (const __attribute__((address_space(1))) void*)g,
      (__attribute__((address_space(3))) void*)l, 16, 0, 0);
}

// ---------------------------------------------------------------- inputs -> fp16 hi/lo planes + row norms (fused)
__global__ __launch_bounds__(192) void conv_init(const float* __restrict__ lf, const float* __restrict__ rf,
                                                 _Float16* __restrict__ hi, _Float16* __restrict__ lo,
                                                 float* __restrict__ norms) {
  int n = blockIdx.x;
  int t = threadIdx.x;
  const float* src = (n < NL) ? lf + (size_t)n * DD : rf + (size_t)(n - NL) * DD;
  float4 v = reinterpret_cast<const float4*>(src)[t];
  _Float16 a0 = (_Float16)v.x, a1 = (_Float16)v.y, a2 = (_Float16)v.z, a3 = (_Float16)v.w;
  typedef _Float16 h4v __attribute__((ext_vector_type(4)));
  h4v hv = {a0, a1, a2, a3};
  h4v lv = {(_Float16)((v.x - (float)a0) * 2048.f), (_Float16)((v.y - (float)a1) * 2048.f),
            (_Float16)((v.z - (float)a2) * 2048.f), (_Float16)((v.w - (float)a3) * 2048.f)};
  size_t idx = (size_t)n * (DD / 4) + t;
  reinterpret_cast<h4v*>(hi)[idx] = hv;
  reinterpret_cast<h4v*>(lo)[idx] = lv;
  float s = v.x * v.x + v.y * v.y + v.z * v.z + v.w * v.w;
  #pragma unroll
  for (int o = 32; o; o >>= 1) s += __shfl_xor(s, o);
  __shared__ float red[3];
  if ((t & 63) == 0) red[t >> 6] = s;
  __syncthreads();
  if (t == 0) norms[n] = sqrtf(red[0] + red[1] + red[2]);
}

// ---------------------------------------------------------------- W[i][k][n] -> Wt[i][n][k] fp16 (hi only)
__global__ __launch_bounds__(256) void transp_W(const float* __restrict__ W, _Float16* __restrict__ Wthi) {
  __shared__ float tile[32][33];
  int kt = blockIdx.x * 32, nt = blockIdx.y * 32, i = blockIdx.z;
  int tx = threadIdx.x & 31, ty = threadIdx.x >> 5;
  const float* Wp = W + ((size_t)i * DD + kt) * DD + nt;
  #pragma unroll
  for (int p = 0; p < 4; ++p) tile[ty + p * 8][tx] = Wp[(size_t)(ty + p * 8) * DD + tx];
  __syncthreads();
  _Float16* oh = Wthi + ((size_t)i * DD + nt) * DD + kt;
  #pragma unroll
  for (int p = 0; p < 4; ++p) {
    int nn = ty + p * 8;
    oh[(size_t)nn * DD + tx] = (_Float16)tile[tx][nn];
  }
}

// ---------------------------------------------------------------- LDS-staged 32x32x16 MFMA GEMM + fused epilogue
// grid 294 (XCD-swizzled -> bx 0..48 row-tile, by 0..5 head-pair). 256 thr = 4 waves.
// Block tile 64 rows x 128 cols; wave = 32 rows x 64 cols (one head). LDS kq pre-swizzled.
__global__ __launch_bounds__(256) void gemm_mfma(const _Float16* __restrict__ Ahi,
                                                 const _Float16* __restrict__ Bhi,
                                                 const float* __restrict__ a_s, const float* __restrict__ a_d,
                                                 const float* __restrict__ bias,
                                                 _Float16* __restrict__ zh,
                                                 float* __restrict__ el, float* __restrict__ er,
                                                 _Float16* __restrict__ ohhi,
                                                 int do_elu, int mode) {
  __shared__ _Float16 smA[2][2048];   // [buf][64*32]
  __shared__ _Float16 smB[2][4096];   // [buf][128*32]
  int t = threadIdx.x;
  // bijective XCD swizzle: 294 = 6*37 + 2*36
  int xcd = blockIdx.x & 7, pos = blockIdx.x >> 3;
  int orig = (xcd < 6 ? xcd * 37 : 222 + (xcd - 6) * 36) + pos;
  int bx = orig / 6, by = orig % 6;
  int m0 = bx * 64, n0 = by * 128;

  int rl = t >> 2;
  int kq_src = (t & 3) ^ ((rl >> 1) & 3);
  const _Float16* pA  = Ahi + (size_t)(m0 + rl) * DD + kq_src * 8;
  const _Float16* pB1 = Bhi + (size_t)(n0 + rl) * DD + kq_src * 8;
  const _Float16* pB2 = Bhi + (size_t)(n0 + 64 + rl) * DD + kq_src * 8;
  int w = t >> 6, l = t & 63;
  int chA  = w * 512;
  int chB2 = 2048 + w * 512;

  int cl = l & 31, hi = l >> 5;
  int rw = (w >> 1) * 32, cw = (w & 1) * 64;
  // A-frag addresses (row = rw+cl, k-halves 0/1)
  int arow = rw + cl;
  int aOff0 = arow * 32 + ((hi)     ^ ((arow >> 1) & 3)) * 8;
  int aOff1 = arow * 32 + ((hi + 2) ^ ((arow >> 1) & 3)) * 8;
  // B-frag addresses, 2 col-tiles
  int brow0 = cw + cl, brow1 = cw + 32 + cl;
  int bOff00 = brow0 * 32 + ((hi)     ^ ((brow0 >> 1) & 3)) * 8;
  int bOff01 = brow0 * 32 + ((hi + 2) ^ ((brow0 >> 1) & 3)) * 8;
  int bOff10 = brow1 * 32 + ((hi)     ^ ((brow1 >> 1) & 3)) * 8;
  int bOff11 = brow1 * 32 + ((hi + 2) ^ ((brow1 >> 1) & 3)) * 8;

  f32x16 acc0, acc1;
  #pragma unroll
  for (int i = 0; i < 16; ++i) { acc0[i] = 0.f; acc1[i] = 0.f; }

  gld16(pA,  &smA[0][chA]);
  gld16(pB1, &smB[0][chA]);
  gld16(pB2, &smB[0][chB2]);
  __syncthreads();

  for (int step = 0; step < NKSTEP; ++step) {
    int buf = step & 1;
    if (step < NKSTEP - 1) {
      int kb = (step + 1) * 32;
      gld16(pA + kb,  &smA[buf ^ 1][chA]);
      gld16(pB1 + kb, &smB[buf ^ 1][chA]);
      gld16(pB2 + kb, &smB[buf ^ 1][chB2]);
    }
    h8 a0  = *reinterpret_cast<const h8*>(&smA[buf][aOff0]);
    h8 a1  = *reinterpret_cast<const h8*>(&smA[buf][aOff1]);
    h8 b00 = *reinterpret_cast<const h8*>(&smB[buf][bOff00]);
    h8 b01 = *reinterpret_cast<const h8*>(&smB[buf][bOff01]);
    h8 b10 = *reinterpret_cast<const h8*>(&smB[buf][bOff10]);
    h8 b11 = *reinterpret_cast<const h8*>(&smB[buf][bOff11]);
    acc0 = MFMA32(a0, b00, acc0);
    acc1 = MFMA32(a0, b10, acc1);
    acc0 = MFMA32(a1, b01, acc0);
    acc1 = MFMA32(a1, b11, acc1);
    __syncthreads();
  }

  // epilogue: C/D layout col=lane&31, row=(reg&3)+8*(reg>>2)+4*(lane>>5)
  int hd = by * 2 + (w & 1);
  float as0 = a_s[hd * DHD + cl],      ad0 = a_d[hd * DHD + cl];
  float as1 = a_s[hd * DHD + 32 + cl], ad1 = a_d[hd * DHD + 32 + cl];
  int c0 = n0 + cw + cl, c1 = c0 + 32;
  float bv0 = bias[c0], bv1 = bias[c1];
  #pragma unroll
  for (int r = 0; r < 16; ++r) {
    int row = m0 + rw + (r & 3) + 8 * (r >> 2) + 4 * hi;
    float z0 = acc0[r], z1 = acc1[r];
    zh[(size_t)row * DD + c0] = (_Float16)z0;
    zh[(size_t)row * DD + c1] = (_Float16)z1;
    bool wh = (mode == 0) ? (row < NL) : (row % 196 != 0);
    if (wh) {
      float o0 = z0 + bv0, o1 = z1 + bv1;
      if (do_elu) {
        o0 = o0 > 0.f ? o0 : expm1f(o0);
        o1 = o1 > 0.f ? o1 : expm1f(o1);
      }
      ohhi[(size_t)row * DD + c0] = (_Float16)o0;
      ohhi[(size_t)row * DD + c1] = (_Float16)o1;
    }
    float s1 = z0 * as0 + z1 * as1;
    float s2 = z0 * ad0 + z1 * ad1;
    #pragma unroll
    for (int o = 1; o < 32; o <<= 1) {   // o=1..16: stays within 32-lane half (uniform row per half)
      s1 += __shfl_xor(s1, o);
      s2 += __shfl_xor(s2, o);
    }
    if (cl == 0) {
      el[(size_t)row * NH + hd] = s1;
      er[(size_t)row * NH + hd] = s2;
    }
  }
}

// ---------------------------------------------------------------- mask via LDS-staged MFMA (NT), FULL hi/lo split
// (mask bits must be exact: a flipped bit is a ~0.2-magnitude output change)
__global__ __launch_bounds__(256) void mask_mfma(const _Float16* __restrict__ Hhi, const _Float16* __restrict__ Hlo,
                                                 const float* __restrict__ norms, unsigned* __restrict__ mask) {
  __shared__ _Float16 sm[2][4][2048];
  __shared__ unsigned mw[64][2];
  int t = threadIdx.x;
  int r0 = blockIdx.x * 64, l0 = blockIdx.y * 64;

  int rl = t >> 2;
  int kq_src = (t & 3) ^ ((t >> 3) & 3);
  int ra = r0 + rl; if (ra >= NL) ra = NL - 1;
  int la = l0 + rl; if (la >= NL) la = NL - 1;
  size_t aoff = (size_t)(NL + ra) * DD + kq_src * 8;
  size_t boff = (size_t)la * DD + kq_src * 8;
  const _Float16* pAhi = Hhi + aoff;
  const _Float16* pAlo = Hlo + aoff;
  const _Float16* pBhi = Hhi + boff;
  const _Float16* pBlo = Hlo + boff;
  int ch = (t >> 6) * 512;

  int ln = t & 63, wv = t >> 6;
  int fr = ln & 15, kg = ln >> 4;
  int kq8 = (kg ^ ((fr >> 1) & 3)) * 8;
  int aRead = (wv * 16 + fr) * 32 + kq8;

  f32x4 zero = {0.f, 0.f, 0.f, 0.f};
  f32x4 acc1[4], acc2[4];
  #pragma unroll
  for (int cg = 0; cg < 4; ++cg) { acc1[cg] = zero; acc2[cg] = zero; }
  if (t < 128) mw[t >> 1][t & 1] = 0u;

  gld16(pAhi, &sm[0][0][ch]);
  gld16(pAlo, &sm[0][1][ch]);
  gld16(pBhi, &sm[0][2][ch]);
  gld16(pBlo, &sm[0][3][ch]);
  __syncthreads();

  for (int step = 0; step < NKSTEP; ++step) {
    int buf = step & 1;
    if (step < NKSTEP - 1) {
      int kb = (step + 1) * 32;
      gld16(pAhi + kb, &sm[buf ^ 1][0][ch]);
      gld16(pAlo + kb, &sm[buf ^ 1][1][ch]);
      gld16(pBhi + kb, &sm[buf ^ 1][2][ch]);
      gld16(pBlo + kb, &sm[buf ^ 1][3][ch]);
    }
    h8 ah = *reinterpret_cast<const h8*>(&sm[buf][0][aRead]);
    h8 al = *reinterpret_cast<const h8*>(&sm[buf][1][aRead]);
    #pragma unroll
    for (int cg = 0; cg < 4; ++cg) {
      int bRead = (cg * 16 + fr) * 32 + kq8;
      h8 bh = *reinterpret_cast<const h8*>(&sm[buf][2][bRead]);
      h8 bl = *reinterpret_cast<const h8*>(&sm[buf][3][bRead]);
      acc1[cg] = MFMA16(ah, bh, acc1[cg]);
      acc2[cg] = MFMA16(ah, bl, acc2[cg]);
      acc2[cg] = MFMA16(al, bh, acc2[cg]);
    }
    __syncthreads();
  }

  int rloc = wv * 16 + kg * 4;
  float nrv[4];
  #pragma unroll
  for (int i = 0; i < 4; ++i) {
    int r = r0 + rloc + i;
    nrv[i] = norms[NL + (r < NL ? r : NL - 1)];
  }
  #pragma unroll
  for (int cg = 0; cg < 4; ++cg) {
    int lloc = cg * 16 + fr;
    int l = l0 + lloc;
    float nlv = norms[l < NL ? l : NL - 1];
    #pragma unroll
    for (int i = 0; i < 4; ++i) {
      int r = r0 + rloc + i;
      float dot = acc1[cg][i] + acc2[cg][i] * (1.f / 2048.f);
      if (r < NL && l < NL && dot > 0.1f * nrv[i] * nlv)
        atomicOr(&mw[rloc + i][lloc >> 5], 1u << (lloc & 31));
    }
  }
  __syncthreads();
  if (t < 128) {
    int rr = t >> 1, w = t & 1;
    int rg = r0 + rr, wg = blockIdx.y * 2 + w;
    if (rg < NL && wg < WPR) mask[(size_t)rg * WPR + wg] = mw[rr][w];
  }
}

// ---------------------------------------------------------------- build neighbor lists from bitmask (once)
__global__ __launch_bounds__(64) void build_csr(const unsigned* __restrict__ mask,
                                                int* __restrict__ nbr, int* __restrict__ deg) {
  int r = blockIdx.x * 64 + threadIdx.x;
  if (r >= NL) return;
  const unsigned* mr = mask + (size_t)r * WPR;
  int* out = nbr + (size_t)r * MAXDEG;
  int cnt = 0;
  #pragma unroll 7
  for (int w = 0; w < WPR; ++w) {
    unsigned m = mr[w];
    while (m) {
      int bpos = __ffs(m) - 1;
      m &= m - 1;
      if (cnt < MAXDEG) out[cnt] = w * 32 + bpos;
      ++cnt;
    }
  }
  deg[r] = cnt < MAXDEG ? cnt : MAXDEG;
}

// ---------------------------------------------------------------- fused sparse bipartite attention (z in fp16)
__global__ __launch_bounds__(768) void bip_fused(const _Float16* __restrict__ zh, const float* __restrict__ el,
                                                 const float* __restrict__ er, const int* __restrict__ nbr,
                                                 const int* __restrict__ deg, const float* __restrict__ bias,
                                                 _Float16* __restrict__ ohhi,
                                                 int do_elu) {
  int r = blockIdx.x;
  int R = NL + r;
  int t = threadIdx.x;
  int dg = deg[r];
  __shared__ int nb_s[MAXDEG];
  __shared__ float wbuf[MAXDEG * NH];
  __shared__ float den_s[NH], wself_s[NH];
  if (t < dg) nb_s[t] = nbr[(size_t)r * MAXDEG + t];
  __syncthreads();
  if (t < dg * NH) {
    int j = t / NH, h2 = t - j * NH;
    wbuf[t] = el[(size_t)nb_s[j] * NH + h2];
  }
  __syncthreads();
  if (t < NH) {
    float er_r = er[(size_t)R * NH + t];
    float s = leaky(el[(size_t)R * NH + t] + er_r);
    float mx = s;
    for (int j = 0; j < dg; ++j) mx = fmaxf(mx, leaky(wbuf[j * NH + t] + er_r));
    float den = 0.f;
    for (int j = 0; j < dg; ++j) {
      float w = expf(leaky(wbuf[j * NH + t] + er_r) - mx);
      wbuf[j * NH + t] = w;
      den += w;
    }
    float ws = expf(s - mx);
    den_s[t] = den + ws;
    wself_s[t] = ws;
  }
  __syncthreads();
  int h2 = t >> 6;
  float acc = wself_s[h2] * (float)zh[(size_t)R * DD + t];
  for (int j = 0; j < dg; ++j)
    acc = fmaf(wbuf[j * NH + h2], (float)zh[(size_t)nb_s[j] * DD + t], acc);
  float o = acc / den_s[h2] + bias[t];
  if (do_elu) o = o > 0.f ? o : expm1f(o);
  ohhi[(size_t)R * DD + t] = (_Float16)o;
}

// ---------------------------------------------------------------- pool attention, (group, head) per block, 4 waves
__global__ __launch_bounds__(256) void pool_attn2(const _Float16* __restrict__ zh, const float* __restrict__ el,
                                                  const float* __restrict__ er, const float* __restrict__ bias,
                                                  _Float16* __restrict__ ohhi,
                                                  float* __restrict__ root_out, int do_elu) {
  int g = blockIdx.x, h = blockIdx.y;
  int base = g * 196;
  int t = threadIdx.x;
  int w = t >> 6, d = t & 63;
  __shared__ float wb[196];
  __shared__ float red[4];
  __shared__ float accP[4][64];
  float er0 = er[(size_t)base * NH + h];
  float lg = -INFINITY;
  if (t < 196) {
    lg = leaky(el[(size_t)(base + t) * NH + h] + er0);
    if (t == 0) lg += LOG2F_;
  }
  float m = lg;
  #pragma unroll
  for (int o = 32; o; o >>= 1) m = fmaxf(m, __shfl_xor(m, o));
  if ((t & 63) == 0) red[w] = m;
  __syncthreads();
  float mx = fmaxf(fmaxf(red[0], red[1]), fmaxf(red[2], red[3]));
  float wgt = (t < 196) ? expf(lg - mx) : 0.f;
  if (t < 196) wb[t] = wgt;
  float dn = wgt;
  #pragma unroll
  for (int o = 32; o; o >>= 1) dn += __shfl_xor(dn, o);
  __syncthreads();
  if ((t & 63) == 0) red[w] = dn;
  __syncthreads();
  float den = red[0] + red[1] + red[2] + red[3];
  float acc = 0.f;
  int p0 = w * 49;
  #pragma unroll 7
  for (int p = p0; p < p0 + 49; ++p)
    acc = fmaf(wb[p], (float)zh[(size_t)(base + p) * DD + h * DHD + d], acc);
  accP[w][d] = acc;
  __syncthreads();
  if (w == 0) {
    float o = (accP[0][d] + accP[1][d] + accP[2][d] + accP[3][d]) / den + bias[h * DHD + d];
    if (do_elu) o = o > 0.f ? o : expm1f(o);
    int c = h * DHD + d;
    ohhi[(size_t)base * DD + c] = (_Float16)o;
    root_out[(size_t)g * DD + c] = o;
  }
}

extern "C" void kernel_launch(void* const* d_in, const int* in_sizes, int n_in,
                              void* d_out, int out_size, void* d_ws, size_t ws_size,
                              hipStream_t stream) {
  const float* l_feat = (const float*)d_in[0];
  const float* r_feat = (const float*)d_in[1];
  const float* W      = (const float*)d_in[2];   // (4, 768, 768)
  const float* a_src  = (const float*)d_in[3];   // (4, 12, 64)
  const float* a_dst  = (const float*)d_in[4];
  const float* b      = (const float*)d_in[5];   // (4, 768)
  float* out = (float*)d_out;

  float* el    = (float*)d_ws;                   // NTOT*NH
  float* er    = el + (size_t)NTOT * NH;         // NTOT*NH
  float* norms = er + (size_t)NTOT * NH;         // NTOT
  float* hroot = norms + NTOT;                   // 16*DD scratch
  unsigned* mask = (unsigned*)(hroot + 16 * DD); // NL*WPR
  int* nbr = (int*)(mask + (size_t)NL * WPR);    // NL*MAXDEG
  int* deg = nbr + (size_t)NL * MAXDEG;          // NL
  _Float16* hhiA = (_Float16*)(deg + NL);        // NTOT*DD halves (ping)
  _Float16* hloA = hhiA + (size_t)NTOT * DD;     // layer-0 lo plane (mask only)
  _Float16* hhiB = hloA + (size_t)NTOT * DD;     // NTOT*DD halves (pong)
  _Float16* Wthi = hhiB + (size_t)NTOT * DD;     // 4*DD*DD halves
  _Float16* zh   = Wthi + (size_t)4 * DD * DD;   // NTOT*DD halves (fp16 z)

  _Float16* hhi[2] = {hhiA, hhiB};

  conv_init<<<NTOT, 192, 0, stream>>>(l_feat, r_feat, hhiA, hloA, norms);
  transp_W<<<dim3(24, 24, 4), 256, 0, stream>>>(W, Wthi);
  mask_mfma<<<dim3(25, 25), 256, 0, stream>>>(hhiA, hloA, norms, mask);
  build_csr<<<(NL + 63) / 64, 64, 0, stream>>>(mask, nbr, deg);

  // ---- 4 bipartite layers (ping-pong h planes: layer L reads L&1, writes (L+1)&1)
  for (int i = 0; i < 4; ++i) {
    const float* bi = b + (size_t)i * DD;
    int do_elu = (i < 3) ? 1 : 0;
    int ib = i & 1, ob = (i + 1) & 1;
    gemm_mfma<<<294, 256, 0, stream>>>(hhi[ib],
        Wthi + (size_t)i * DD * DD,
        a_src + (size_t)i * NH * DHD, a_dst + (size_t)i * NH * DHD,
        bi, zh, el, er, hhi[ob], do_elu, 0);
    bip_fused<<<NL, 768, 0, stream>>>(zh, el, er, nbr, deg, bi, hhi[ob], do_elu);
  }

  // ---- 4 pool layers
  for (int i = 0; i < 4; ++i) {
    const float* bi = b + (size_t)i * DD;
    int do_elu = (i < 3) ? 1 : 0;
    int L = 4 + i;
    int ib = L & 1, ob = (L + 1) & 1;
    gemm_mfma<<<294, 256, 0, stream>>>(hhi[ib],
        Wthi + (size_t)i * DD * DD,
        a_src + (size_t)i * NH * DHD, a_dst + (size_t)i * NH * DHD,
        bi, zh, el, er, hhi[ob], do_elu, 1);
    pool_attn2<<<dim3(16, NH), 256, 0, stream>>>(zh, el, er, bi, hhi[ob],
        (i == 3) ? out : hroot, do_elu);
  }
}

// Round 12
// 295.953 us; speedup vs baseline: 1.0415x; 1.0415x over previous
//
#include <hip/hip_runtime.h>
#include <math.h>

// Problem constants
#define NL    1568          // left nodes (B*P)
#define NTOT  3136          // total nodes
#define DD    768           // feature dim
#define NH    12            // heads
#define DHD   64            // head dim
#define WPR   49            // mask words per row (1568/32)
#define MAXDEG 64           // neighbor-list capacity
#define NKSTEP 24           // 768 / 32
#define LOG2F_ 0.69314718055994530942f

typedef _Float16 h8 __attribute__((ext_vector_type(8)));
typedef float f32x4 __attribute__((ext_vector_type(4)));
typedef float f32x16 __attribute__((ext_vector_type(16)));
#define MFMA16(a, b, c) __builtin_amdgcn_mfma_f32_16x16x32_f16(a, b, c, 0, 0, 0)
#define MFMA32(a, b, c) __builtin_amdgcn_mfma_f32_32x32x16_f16(a, b, c, 0, 0, 0)

__device__ __forceinline__ float leaky(float x) { return x > 0.f ? x : 0.2f * x; }

__device__ __forceinline__ void gld16(const _Float16* g, _Float16* l) {
  __builtin_amdgcn_global_load_lds(
      (const __attribute__((address_space(1))) void*)g,
      (__attribute__((address_space(3))) void*)l, 16, 0, 0);
}

// ---------------------------------------------------------------- inputs -> fp16 hi/lo planes + row norms (fused)
__global__ __launch_bounds__(192) void conv_init(const float* __restrict__ lf, const float* __restrict__ rf,
                                                 _Float16* __restrict__ hi, _Float16* __restrict__ lo,
                                                 float* __restrict__ norms) {
  int n = blockIdx.x;
  int t = threadIdx.x;
  const float* src = (n < NL) ? lf + (size_t)n * DD : rf + (size_t)(n - NL) * DD;
  float4 v = reinterpret_cast<const float4*>(src)[t];
  _Float16 a0 = (_Float16)v.x, a1 = (_Float16)v.y, a2 = (_Float16)v.z, a3 = (_Float16)v.w;
  typedef _Float16 h4v __attribute__((ext_vector_type(4)));
  h4v hv = {a0, a1, a2, a3};
  h4v lv = {(_Float16)((v.x - (float)a0) * 2048.f), (_Float16)((v.y - (float)a1) * 2048.f),
            (_Float16)((v.z - (float)a2) * 2048.f), (_Float16)((v.w - (float)a3) * 2048.f)};
  size_t idx = (size_t)n * (DD / 4) + t;
  reinterpret_cast<h4v*>(hi)[idx] = hv;
  reinterpret_cast<h4v*>(lo)[idx] = lv;
  float s = v.x * v.x + v.y * v.y + v.z * v.z + v.w * v.w;
  #pragma unroll
  for (int o = 32; o; o >>= 1) s += __shfl_xor(s, o);
  __shared__ float red[3];
  if ((t & 63) == 0) red[t >> 6] = s;
  __syncthreads();
  if (t == 0) norms[n] = sqrtf(red[0] + red[1] + red[2]);
}

// ---------------------------------------------------------------- W[i][k][n] -> Wt[i][n][k] fp16 (hi only)
__global__ __launch_bounds__(256) void transp_W(const float* __restrict__ W, _Float16* __restrict__ Wthi) {
  __shared__ float tile[32][33];
  int kt = blockIdx.x * 32, nt = blockIdx.y * 32, i = blockIdx.z;
  int tx = threadIdx.x & 31, ty = threadIdx.x >> 5;
  const float* Wp = W + ((size_t)i * DD + kt) * DD + nt;
  #pragma unroll
  for (int p = 0; p < 4; ++p) tile[ty + p * 8][tx] = Wp[(size_t)(ty + p * 8) * DD + tx];
  __syncthreads();
  _Float16* oh = Wthi + ((size_t)i * DD + nt) * DD + kt;
  #pragma unroll
  for (int p = 0; p < 4; ++p) {
    int nn = ty + p * 8;
    oh[(size_t)nn * DD + tx] = (_Float16)tile[tx][nn];
  }
}

// ---------------------------------------------------------------- LDS-staged 32x32x16 MFMA GEMM + fused epilogue
// grid 588 (XCD-swizzled). Block = 32 rows x 128 cols, 4 waves; wave = 32x32 out (2 MFMA/K-step).
// 2352 waves total (2.3/SIMD). LDS kq pre-swizzled. el/er via LDS partial combine across wave pairs.
__global__ __launch_bounds__(256) void gemm_mfma(const _Float16* __restrict__ Ahi,
                                                 const _Float16* __restrict__ Bhi,
                                                 const float* __restrict__ a_s, const float* __restrict__ a_d,
                                                 const float* __restrict__ bias,
                                                 _Float16* __restrict__ zh,
                                                 float* __restrict__ el, float* __restrict__ er,
                                                 _Float16* __restrict__ ohhi,
                                                 int do_elu, int mode) {
  __shared__ _Float16 smA[2][1024];   // [buf][32*32]
  __shared__ _Float16 smB[2][4096];   // [buf][128*32]
  __shared__ float elp[4][2][16], erp[4][2][16];
  int t = threadIdx.x;
  // bijective XCD swizzle: 588 = 4*74 + 4*73
  int xcd = blockIdx.x & 7, pos = blockIdx.x >> 3;
  int orig = (xcd < 4 ? xcd * 74 : 296 + (xcd - 4) * 73) + pos;
  int bx = orig / 6, by = orig % 6;
  int m0 = bx * 32, n0 = by * 128;

  int w = t >> 6, l = t & 63;
  // staging: A (32x32, t<128: slot t -> row t>>2, kq t&3), B (128x32, slots t and t+256)
  int rlA = t >> 2;
  int kqA = (t & 3) ^ ((rlA >> 1) & 3);
  const _Float16* pA = Ahi + (size_t)(m0 + (rlA & 31)) * DD + kqA * 8;
  int rlB0 = t >> 2, rlB1 = 64 + rlB0;
  int kqB0 = (t & 3) ^ ((rlB0 >> 1) & 3);
  int kqB1 = (t & 3) ^ ((rlB1 >> 1) & 3);
  const _Float16* pB0 = Bhi + (size_t)(n0 + rlB0) * DD + kqB0 * 8;
  const _Float16* pB1 = Bhi + (size_t)(n0 + rlB1) * DD + kqB1 * 8;
  int chA  = w * 512;            // waves 0,1 only
  int chB0 = w * 512;
  int chB1 = 2048 + w * 512;

  int cl = l & 31, hi = l >> 5;
  int cw = w * 32;
  // fragment LDS offsets (halves), same XOR as staging
  int aOff0 = cl * 32 + ((hi)     ^ ((cl >> 1) & 3)) * 8;
  int aOff1 = cl * 32 + ((hi + 2) ^ ((cl >> 1) & 3)) * 8;
  int brow = cw + cl;
  int bOff0 = brow * 32 + ((hi)     ^ ((brow >> 1) & 3)) * 8;
  int bOff1 = brow * 32 + ((hi + 2) ^ ((brow >> 1) & 3)) * 8;

  f32x16 acc;
  #pragma unroll
  for (int i = 0; i < 16; ++i) acc[i] = 0.f;

  if (t < 128) gld16(pA, &smA[0][chA]);
  gld16(pB0, &smB[0][chB0]);
  gld16(pB1, &smB[0][chB1]);
  __syncthreads();

  for (int step = 0; step < NKSTEP; ++step) {
    int buf = step & 1;
    if (step < NKSTEP - 1) {
      int kb = (step + 1) * 32;
      if (t < 128) gld16(pA + kb, &smA[buf ^ 1][chA]);
      gld16(pB0 + kb, &smB[buf ^ 1][chB0]);
      gld16(pB1 + kb, &smB[buf ^ 1][chB1]);
    }
    h8 a0 = *reinterpret_cast<const h8*>(&smA[buf][aOff0]);
    h8 a1 = *reinterpret_cast<const h8*>(&smA[buf][aOff1]);
    h8 b0 = *reinterpret_cast<const h8*>(&smB[buf][bOff0]);
    h8 b1 = *reinterpret_cast<const h8*>(&smB[buf][bOff1]);
    acc = MFMA32(a0, b0, acc);
    acc = MFMA32(a1, b1, acc);
    __syncthreads();
  }

  // epilogue: C/D layout col=lane&31, row=(reg&3)+8*(reg>>2)+4*(lane>>5)  [HW-validated R10]
  int hd = by * 2 + (w >> 1);           // waves 0,1 -> head by*2 ; waves 2,3 -> by*2+1
  float asv = a_s[hd * DHD + (w & 1) * 32 + cl];
  float adv = a_d[hd * DHD + (w & 1) * 32 + cl];
  int c = n0 + cw + cl;
  float bv = bias[c];
  #pragma unroll
  for (int r = 0; r < 16; ++r) {
    int row = m0 + (r & 3) + 8 * (r >> 2) + 4 * hi;
    float z = acc[r];
    zh[(size_t)row * DD + c] = (_Float16)z;
    bool wh = (mode == 0) ? (row < NL) : (row % 196 != 0);
    if (wh) {
      float o = z + bv;
      if (do_elu) o = o > 0.f ? o : expm1f(o);
      ohhi[(size_t)row * DD + c] = (_Float16)o;
    }
    float s1 = z * asv, s2 = z * adv;
    #pragma unroll
    for (int o = 1; o < 32; o <<= 1) {   // o=1..16: within 32-lane half
      s1 += __shfl_xor(s1, o);
      s2 += __shfl_xor(s2, o);
    }
    if (cl == 0) { elp[w][hi][r] = s1; erp[w][hi][r] = s2; }
  }
  __syncthreads();
  // combine wave pairs (0+1 -> head by*2, 2+3 -> by*2+1): 64 threads finalize
  if (t < 64) {
    int hp = t >> 5, hi2 = (t >> 4) & 1, r2 = t & 15;
    int row = m0 + (r2 & 3) + 8 * (r2 >> 2) + 4 * hi2;
    int hd2 = by * 2 + hp;
    el[(size_t)row * NH + hd2] = elp[2 * hp][hi2][r2] + elp[2 * hp + 1][hi2][r2];
    er[(size_t)row * NH + hd2] = erp[2 * hp][hi2][r2] + erp[2 * hp + 1][hi2][r2];
  }
}

// ---------------------------------------------------------------- mask via LDS-staged MFMA (NT), FULL hi/lo split
// (mask bits must be exact: a flipped bit is a ~0.2-magnitude output change)
__global__ __launch_bounds__(256) void mask_mfma(const _Float16* __restrict__ Hhi, const _Float16* __restrict__ Hlo,
                                                 const float* __restrict__ norms, unsigned* __restrict__ mask) {
  __shared__ _Float16 sm[2][4][2048];
  __shared__ unsigned mw[64][2];
  int t = threadIdx.x;
  int r0 = blockIdx.x * 64, l0 = blockIdx.y * 64;

  int rl = t >> 2;
  int kq_src = (t & 3) ^ ((t >> 3) & 3);
  int ra = r0 + rl; if (ra >= NL) ra = NL - 1;
  int la = l0 + rl; if (la >= NL) la = NL - 1;
  size_t aoff = (size_t)(NL + ra) * DD + kq_src * 8;
  size_t boff = (size_t)la * DD + kq_src * 8;
  const _Float16* pAhi = Hhi + aoff;
  const _Float16* pAlo = Hlo + aoff;
  const _Float16* pBhi = Hhi + boff;
  const _Float16* pBlo = Hlo + boff;
  int ch = (t >> 6) * 512;

  int ln = t & 63, wv = t >> 6;
  int fr = ln & 15, kg = ln >> 4;
  int kq8 = (kg ^ ((fr >> 1) & 3)) * 8;
  int aRead = (wv * 16 + fr) * 32 + kq8;

  f32x4 zero = {0.f, 0.f, 0.f, 0.f};
  f32x4 acc1[4], acc2[4];
  #pragma unroll
  for (int cg = 0; cg < 4; ++cg) { acc1[cg] = zero; acc2[cg] = zero; }
  if (t < 128) mw[t >> 1][t & 1] = 0u;

  gld16(pAhi, &sm[0][0][ch]);
  gld16(pAlo, &sm[0][1][ch]);
  gld16(pBhi, &sm[0][2][ch]);
  gld16(pBlo, &sm[0][3][ch]);
  __syncthreads();

  for (int step = 0; step < NKSTEP; ++step) {
    int buf = step & 1;
    if (step < NKSTEP - 1) {
      int kb = (step + 1) * 32;
      gld16(pAhi + kb, &sm[buf ^ 1][0][ch]);
      gld16(pAlo + kb, &sm[buf ^ 1][1][ch]);
      gld16(pBhi + kb, &sm[buf ^ 1][2][ch]);
      gld16(pBlo + kb, &sm[buf ^ 1][3][ch]);
    }
    h8 ah = *reinterpret_cast<const h8*>(&sm[buf][0][aRead]);
    h8 al = *reinterpret_cast<const h8*>(&sm[buf][1][aRead]);
    #pragma unroll
    for (int cg = 0; cg < 4; ++cg) {
      int bRead = (cg * 16 + fr) * 32 + kq8;
      h8 bh = *reinterpret_cast<const h8*>(&sm[buf][2][bRead]);
      h8 bl = *reinterpret_cast<const h8*>(&sm[buf][3][bRead]);
      acc1[cg] = MFMA16(ah, bh, acc1[cg]);
      acc2[cg] = MFMA16(ah, bl, acc2[cg]);
      acc2[cg] = MFMA16(al, bh, acc2[cg]);
    }
    __syncthreads();
  }

  int rloc = wv * 16 + kg * 4;
  float nrv[4];
  #pragma unroll
  for (int i = 0; i < 4; ++i) {
    int r = r0 + rloc + i;
    nrv[i] = norms[NL + (r < NL ? r : NL - 1)];
  }
  #pragma unroll
  for (int cg = 0; cg < 4; ++cg) {
    int lloc = cg * 16 + fr;
    int l = l0 + lloc;
    float nlv = norms[l < NL ? l : NL - 1];
    #pragma unroll
    for (int i = 0; i < 4; ++i) {
      int r = r0 + rloc + i;
      float dot = acc1[cg][i] + acc2[cg][i] * (1.f / 2048.f);
      if (r < NL && l < NL && dot > 0.1f * nrv[i] * nlv)
        atomicOr(&mw[rloc + i][lloc >> 5], 1u << (lloc & 31));
    }
  }
  __syncthreads();
  if (t < 128) {
    int rr = t >> 1, w = t & 1;
    int rg = r0 + rr, wg = blockIdx.y * 2 + w;
    if (rg < NL && wg < WPR) mask[(size_t)rg * WPR + wg] = mw[rr][w];
  }
}

// ---------------------------------------------------------------- build neighbor lists from bitmask (once)
__global__ __launch_bounds__(64) void build_csr(const unsigned* __restrict__ mask,
                                                int* __restrict__ nbr, int* __restrict__ deg) {
  int r = blockIdx.x * 64 + threadIdx.x;
  if (r >= NL) return;
  const unsigned* mr = mask + (size_t)r * WPR;
  int* out = nbr + (size_t)r * MAXDEG;
  int cnt = 0;
  #pragma unroll 7
  for (int w = 0; w < WPR; ++w) {
    unsigned m = mr[w];
    while (m) {
      int bpos = __ffs(m) - 1;
      m &= m - 1;
      if (cnt < MAXDEG) out[cnt] = w * 32 + bpos;
      ++cnt;
    }
  }
  deg[r] = cnt < MAXDEG ? cnt : MAXDEG;
}

// ---------------------------------------------------------------- fused sparse bipartite attention (z in fp16)
__global__ __launch_bounds__(768) void bip_fused(const _Float16* __restrict__ zh, const float* __restrict__ el,
                                                 const float* __restrict__ er, const int* __restrict__ nbr,
                                                 const int* __restrict__ deg, const float* __restrict__ bias,
                                                 _Float16* __restrict__ ohhi,
                                                 int do_elu) {
  int r = blockIdx.x;
  int R = NL + r;
  int t = threadIdx.x;
  int dg = deg[r];
  __shared__ int nb_s[MAXDEG];
  __shared__ float wbuf[MAXDEG * NH];
  __shared__ float den_s[NH], wself_s[NH];
  if (t < dg) nb_s[t] = nbr[(size_t)r * MAXDEG + t];
  __syncthreads();
  if (t < dg * NH) {
    int j = t / NH, h2 = t - j * NH;
    wbuf[t] = el[(size_t)nb_s[j] * NH + h2];
  }
  __syncthreads();
  if (t < NH) {
    float er_r = er[(size_t)R * NH + t];
    float s = leaky(el[(size_t)R * NH + t] + er_r);
    float mx = s;
    for (int j = 0; j < dg; ++j) mx = fmaxf(mx, leaky(wbuf[j * NH + t] + er_r));
    float den = 0.f;
    for (int j = 0; j < dg; ++j) {
      float w = expf(leaky(wbuf[j * NH + t] + er_r) - mx);
      wbuf[j * NH + t] = w;
      den += w;
    }
    float ws = expf(s - mx);
    den_s[t] = den + ws;
    wself_s[t] = ws;
  }
  __syncthreads();
  int h2 = t >> 6;
  float acc = wself_s[h2] * (float)zh[(size_t)R * DD + t];
  for (int j = 0; j < dg; ++j)
    acc = fmaf(wbuf[j * NH + h2], (float)zh[(size_t)nb_s[j] * DD + t], acc);
  float o = acc / den_s[h2] + bias[t];
  if (do_elu) o = o > 0.f ? o : expm1f(o);
  ohhi[(size_t)R * DD + t] = (_Float16)o;
}

// ---------------------------------------------------------------- pool attention, (group, head) per block, 4 waves
__global__ __launch_bounds__(256) void pool_attn2(const _Float16* __restrict__ zh, const float* __restrict__ el,
                                                  const float* __restrict__ er, const float* __restrict__ bias,
                                                  _Float16* __restrict__ ohhi,
                                                  float* __restrict__ root_out, int do_elu) {
  int g = blockIdx.x, h = blockIdx.y;
  int base = g * 196;
  int t = threadIdx.x;
  int w = t >> 6, d = t & 63;
  __shared__ float wb[196];
  __shared__ float red[4];
  __shared__ float accP[4][64];
  float er0 = er[(size_t)base * NH + h];
  float lg = -INFINITY;
  if (t < 196) {
    lg = leaky(el[(size_t)(base + t) * NH + h] + er0);
    if (t == 0) lg += LOG2F_;
  }
  float m = lg;
  #pragma unroll
  for (int o = 32; o; o >>= 1) m = fmaxf(m, __shfl_xor(m, o));
  if ((t & 63) == 0) red[w] = m;
  __syncthreads();
  float mx = fmaxf(fmaxf(red[0], red[1]), fmaxf(red[2], red[3]));
  float wgt = (t < 196) ? expf(lg - mx) : 0.f;
  if (t < 196) wb[t] = wgt;
  float dn = wgt;
  #pragma unroll
  for (int o = 32; o; o >>= 1) dn += __shfl_xor(dn, o);
  __syncthreads();
  if ((t & 63) == 0) red[w] = dn;
  __syncthreads();
  float den = red[0] + red[1] + red[2] + red[3];
  float acc = 0.f;
  int p0 = w * 49;
  #pragma unroll 7
  for (int p = p0; p < p0 + 49; ++p)
    acc = fmaf(wb[p], (float)zh[(size_t)(base + p) * DD + h * DHD + d], acc);
  accP[w][d] = acc;
  __syncthreads();
  if (w == 0) {
    float o = (accP[0][d] + accP[1][d] + accP[2][d] + accP[3][d]) / den + bias[h * DHD + d];
    if (do_elu) o = o > 0.f ? o : expm1f(o);
    int c = h * DHD + d;
    ohhi[(size_t)base * DD + c] = (_Float16)o;
    root_out[(size_t)g * DD + c] = o;
  }
}

extern "C" void kernel_launch(void* const* d_in, const int* in_sizes, int n_in,
                              void* d_out, int out_size, void* d_ws, size_t ws_size,
                              hipStream_t stream) {
  const float* l_feat = (const float*)d_in[0];
  const float* r_feat = (const float*)d_in[1];
  const float* W      = (const float*)d_in[2];   // (4, 768, 768)
  const float* a_src  = (const float*)d_in[3];   // (4, 12, 64)
  const float* a_dst  = (const float*)d_in[4];
  const float* b      = (const float*)d_in[5];   // (4, 768)
  float* out = (float*)d_out;

  float* el    = (float*)d_ws;                   // NTOT*NH
  float* er    = el + (size_t)NTOT * NH;         // NTOT*NH
  float* norms = er + (size_t)NTOT * NH;         // NTOT
  float* hroot = norms + NTOT;                   // 16*DD scratch
  unsigned* mask = (unsigned*)(hroot + 16 * DD); // NL*WPR
  int* nbr = (int*)(mask + (size_t)NL * WPR);    // NL*MAXDEG
  int* deg = nbr + (size_t)NL * MAXDEG;          // NL
  _Float16* hhiA = (_Float16*)(deg + NL);        // NTOT*DD halves (ping)
  _Float16* hloA = hhiA + (size_t)NTOT * DD;     // layer-0 lo plane (mask only)
  _Float16* hhiB = hloA + (size_t)NTOT * DD;     // NTOT*DD halves (pong)
  _Float16* Wthi = hhiB + (size_t)NTOT * DD;     // 4*DD*DD halves
  _Float16* zh   = Wthi + (size_t)4 * DD * DD;   // NTOT*DD halves (fp16 z)

  _Float16* hhi[2] = {hhiA, hhiB};

  conv_init<<<NTOT, 192, 0, stream>>>(l_feat, r_feat, hhiA, hloA, norms);
  transp_W<<<dim3(24, 24, 4), 256, 0, stream>>>(W, Wthi);
  mask_mfma<<<dim3(25, 25), 256, 0, stream>>>(hhiA, hloA, norms, mask);
  build_csr<<<(NL + 63) / 64, 64, 0, stream>>>(mask, nbr, deg);

  // ---- 4 bipartite layers (ping-pong h planes: layer L reads L&1, writes (L+1)&1)
  for (int i = 0; i < 4; ++i) {
    const float* bi = b + (size_t)i * DD;
    int do_elu = (i < 3) ? 1 : 0;
    int ib = i & 1, ob = (i + 1) & 1;
    gemm_mfma<<<588, 256, 0, stream>>>(hhi[ib],
        Wthi + (size_t)i * DD * DD,
        a_src + (size_t)i * NH * DHD, a_dst + (size_t)i * NH * DHD,
        bi, zh, el, er, hhi[ob], do_elu, 0);
    bip_fused<<<NL, 768, 0, stream>>>(zh, el, er, nbr, deg, bi, hhi[ob], do_elu);
  }

  // ---- 4 pool layers
  for (int i = 0; i < 4; ++i) {
    const float* bi = b + (size_t)i * DD;
    int do_elu = (i < 3) ? 1 : 0;
    int L = 4 + i;
    int ib = L & 1, ob = (L + 1) & 1;
    gemm_mfma<<<588, 256, 0, stream>>>(hhi[ib],
        Wthi + (size_t)i * DD * DD,
        a_src + (size_t)i * NH * DHD, a_dst + (size_t)i * NH * DHD,
        bi, zh, el, er, hhi[ob], do_elu, 1);
    pool_attn2<<<dim3(16, NH), 256, 0, stream>>>(zh, el, er, bi, hhi[ob],
        (i == 3) ? out : hroot, do_elu);
  }
}

// Round 13
// 281.136 us; speedup vs baseline: 1.0964x; 1.0527x over previous
//
#include <hip/hip_runtime.h>
#include <math.h>

// Problem constants
#define NL    1568          // left nodes (B*P)
#define NTOT  3136          // total nodes
#define DD    768           // feature dim
#define NH    12            // heads
#define DHD   64            // head dim
#define WPR   49            // mask words per row (1568/32)
#define MAXDEG 64           // neighbor-list capacity
#define NKSTEP 24           // 768 / 32 (mask kernel)
#define NK64   12           // 768 / 64 (gemm kernel)
#define LOG2F_ 0.69314718055994530942f

typedef _Float16 h8 __attribute__((ext_vector_type(8)));
typedef float f32x4 __attribute__((ext_vector_type(4)));
#define MFMA16(a, b, c) __builtin_amdgcn_mfma_f32_16x16x32_f16(a, b, c, 0, 0, 0)

__device__ __forceinline__ float leaky(float x) { return x > 0.f ? x : 0.2f * x; }

__device__ __forceinline__ void gld16(const _Float16* g, _Float16* l) {
  __builtin_amdgcn_global_load_lds(
      (const __attribute__((address_space(1))) void*)g,
      (__attribute__((address_space(3))) void*)l, 16, 0, 0);
}

// ---------------------------------------------------------------- inputs -> fp16 hi/lo planes + row norms (fused)
__global__ __launch_bounds__(192) void conv_init(const float* __restrict__ lf, const float* __restrict__ rf,
                                                 _Float16* __restrict__ hi, _Float16* __restrict__ lo,
                                                 float* __restrict__ norms) {
  int n = blockIdx.x;
  int t = threadIdx.x;
  const float* src = (n < NL) ? lf + (size_t)n * DD : rf + (size_t)(n - NL) * DD;
  float4 v = reinterpret_cast<const float4*>(src)[t];
  _Float16 a0 = (_Float16)v.x, a1 = (_Float16)v.y, a2 = (_Float16)v.z, a3 = (_Float16)v.w;
  typedef _Float16 h4v __attribute__((ext_vector_type(4)));
  h4v hv = {a0, a1, a2, a3};
  h4v lv = {(_Float16)((v.x - (float)a0) * 2048.f), (_Float16)((v.y - (float)a1) * 2048.f),
            (_Float16)((v.z - (float)a2) * 2048.f), (_Float16)((v.w - (float)a3) * 2048.f)};
  size_t idx = (size_t)n * (DD / 4) + t;
  reinterpret_cast<h4v*>(hi)[idx] = hv;
  reinterpret_cast<h4v*>(lo)[idx] = lv;
  float s = v.x * v.x + v.y * v.y + v.z * v.z + v.w * v.w;
  #pragma unroll
  for (int o = 32; o; o >>= 1) s += __shfl_xor(s, o);
  __shared__ float red[3];
  if ((t & 63) == 0) red[t >> 6] = s;
  __syncthreads();
  if (t == 0) norms[n] = sqrtf(red[0] + red[1] + red[2]);
}

// ---------------------------------------------------------------- W[i][k][n] -> Wt[i][n][k] fp16 (hi only)
__global__ __launch_bounds__(256) void transp_W(const float* __restrict__ W, _Float16* __restrict__ Wthi) {
  __shared__ float tile[32][33];
  int kt = blockIdx.x * 32, nt = blockIdx.y * 32, i = blockIdx.z;
  int tx = threadIdx.x & 31, ty = threadIdx.x >> 5;
  const float* Wp = W + ((size_t)i * DD + kt) * DD + nt;
  #pragma unroll
  for (int p = 0; p < 4; ++p) tile[ty + p * 8][tx] = Wp[(size_t)(ty + p * 8) * DD + tx];
  __syncthreads();
  _Float16* oh = Wthi + ((size_t)i * DD + nt) * DD + kt;
  #pragma unroll
  for (int p = 0; p < 4; ++p) {
    int nn = ty + p * 8;
    oh[(size_t)nn * DD + tx] = (_Float16)tile[tx][nn];
  }
}

// ---------------------------------------------------------------- LDS-staged MFMA GEMM, BK=64 (12 steps), fused epilogue
// grid 588 (XCD-swizzled -> bx 0..48 row-tile, by 0..11 head). 256 thr = 4 waves x 16 rows.
// LDS 64x64-half tiles; 8 slots/row, swizzle kq' = kq ^ (row&7). 2352 waves (2.3/SIMD).
__global__ __launch_bounds__(256) void gemm_mfma(const _Float16* __restrict__ Ahi,
                                                 const _Float16* __restrict__ Bhi,
                                                 const float* __restrict__ a_s, const float* __restrict__ a_d,
                                                 const float* __restrict__ bias,
                                                 _Float16* __restrict__ zh,
                                                 float* __restrict__ el, float* __restrict__ er,
                                                 _Float16* __restrict__ ohhi,
                                                 int do_elu, int mode) {
  __shared__ _Float16 smA[2][4096];   // [buf][64 rows * 64 halves]
  __shared__ _Float16 smB[2][4096];
  int t = threadIdx.x;
  // bijective XCD swizzle: 588 = 4*74 + 4*73
  int xcd = blockIdx.x & 7, pos = blockIdx.x >> 3;
  int orig = (xcd < 4 ? xcd * 74 : 296 + (xcd - 4) * 73) + pos;
  int bx = orig / 12, by = orig % 12;
  int m0 = bx * 64, n0 = by * 64;

  // staging: thread t stages slots t (rows 0..31) and t+256 (rows 32..63) of each tile
  int rs = t >> 3;                        // 0..31
  int kq0 = (t & 7) ^ (rs & 7);           // source slot (same XOR for row+32)
  const _Float16* pA0 = Ahi + (size_t)(m0 + rs) * DD + kq0 * 8;
  const _Float16* pA1 = pA0 + (size_t)32 * DD;
  const _Float16* pB0 = Bhi + (size_t)(n0 + rs) * DD + kq0 * 8;
  const _Float16* pB1 = pB0 + (size_t)32 * DD;
  int w = t >> 6, l = t & 63;
  int ch0 = w * 512;                      // halves: slots w*64+lane
  int ch1 = 2048 + w * 512;               // slots 256 + w*64+lane

  int fr = l & 15, kg = l >> 4;
  // fragment LDS offsets (halves): row*64 + slot'*8, slot' = (kk*4+kg) ^ (row&7)
  int aO[2], bO[4][2];
  #pragma unroll
  for (int kk = 0; kk < 2; ++kk) {
    int arow = w * 16 + fr;
    aO[kk] = arow * 64 + (((kk * 4 + kg) ^ (arow & 7)) * 8);
    #pragma unroll
    for (int cg = 0; cg < 4; ++cg) {
      int brow = cg * 16 + fr;
      bO[cg][kk] = brow * 64 + (((kk * 4 + kg) ^ (brow & 7)) * 8);
    }
  }

  f32x4 zero = {0.f, 0.f, 0.f, 0.f};
  f32x4 acc[4];
  #pragma unroll
  for (int cg = 0; cg < 4; ++cg) acc[cg] = zero;

  gld16(pA0, &smA[0][ch0]);
  gld16(pA1, &smA[0][ch1]);
  gld16(pB0, &smB[0][ch0]);
  gld16(pB1, &smB[0][ch1]);
  __syncthreads();

  for (int step = 0; step < NK64; ++step) {
    int buf = step & 1;
    if (step < NK64 - 1) {
      int kb = (step + 1) * 64;
      gld16(pA0 + kb, &smA[buf ^ 1][ch0]);
      gld16(pA1 + kb, &smA[buf ^ 1][ch1]);
      gld16(pB0 + kb, &smB[buf ^ 1][ch0]);
      gld16(pB1 + kb, &smB[buf ^ 1][ch1]);
    }
    #pragma unroll
    for (int kk = 0; kk < 2; ++kk) {
      h8 a = *reinterpret_cast<const h8*>(&smA[buf][aO[kk]]);
      #pragma unroll
      for (int cg = 0; cg < 4; ++cg) {
        h8 b = *reinterpret_cast<const h8*>(&smB[buf][bO[cg][kk]]);
        acc[cg] = MFMA16(a, b, acc[cg]);
      }
    }
    __syncthreads();
  }

  // epilogue (16x16 C/D layout: col=lane&15, row=(lane>>4)*4+reg)
  int head = by;
  int orow = m0 + w * 16 + kg * 4;
  #pragma unroll
  for (int i = 0; i < 4; ++i) {
    int r = orow + i;
    bool wh = (mode == 0) ? (r < NL) : (r % 196 != 0);
    #pragma unroll
    for (int cg = 0; cg < 4; ++cg) {
      int c = n0 + cg * 16 + fr;
      float z = acc[cg][i];
      zh[(size_t)r * DD + c] = (_Float16)z;
      if (wh) {
        float o = z + bias[c];
        if (do_elu) o = o > 0.f ? o : expm1f(o);
        ohhi[(size_t)r * DD + c] = (_Float16)o;
      }
    }
  }
  // fused el/er (this block owns head == by)
  float asv[4], adv[4];
  #pragma unroll
  for (int cg = 0; cg < 4; ++cg) {
    asv[cg] = a_s[head * DHD + cg * 16 + fr];
    adv[cg] = a_d[head * DHD + cg * 16 + fr];
  }
  #pragma unroll
  for (int i = 0; i < 4; ++i) {
    float s1 = 0.f, s2 = 0.f;
    #pragma unroll
    for (int cg = 0; cg < 4; ++cg) {
      s1 = fmaf(acc[cg][i], asv[cg], s1);
      s2 = fmaf(acc[cg][i], adv[cg], s2);
    }
    #pragma unroll
    for (int o = 1; o < 16; o <<= 1) {
      s1 += __shfl_xor(s1, o);
      s2 += __shfl_xor(s2, o);
    }
    if (fr == 0) {
      el[(size_t)(orow + i) * NH + head] = s1;
      er[(size_t)(orow + i) * NH + head] = s2;
    }
  }
}

// ---------------------------------------------------------------- mask via LDS-staged MFMA (NT), FULL hi/lo split
// (mask bits must be exact: a flipped bit is a ~0.2-magnitude output change)
__global__ __launch_bounds__(256) void mask_mfma(const _Float16* __restrict__ Hhi, const _Float16* __restrict__ Hlo,
                                                 const float* __restrict__ norms, unsigned* __restrict__ mask) {
  __shared__ _Float16 sm[2][4][2048];
  __shared__ unsigned mw[64][2];
  int t = threadIdx.x;
  int r0 = blockIdx.x * 64, l0 = blockIdx.y * 64;

  int rl = t >> 2;
  int kq_src = (t & 3) ^ ((t >> 3) & 3);
  int ra = r0 + rl; if (ra >= NL) ra = NL - 1;
  int la = l0 + rl; if (la >= NL) la = NL - 1;
  size_t aoff = (size_t)(NL + ra) * DD + kq_src * 8;
  size_t boff = (size_t)la * DD + kq_src * 8;
  const _Float16* pAhi = Hhi + aoff;
  const _Float16* pAlo = Hlo + aoff;
  const _Float16* pBhi = Hhi + boff;
  const _Float16* pBlo = Hlo + boff;
  int ch = (t >> 6) * 512;

  int ln = t & 63, wv = t >> 6;
  int fr = ln & 15, kg = ln >> 4;
  int kq8 = (kg ^ ((fr >> 1) & 3)) * 8;
  int aRead = (wv * 16 + fr) * 32 + kq8;

  f32x4 zero = {0.f, 0.f, 0.f, 0.f};
  f32x4 acc1[4], acc2[4];
  #pragma unroll
  for (int cg = 0; cg < 4; ++cg) { acc1[cg] = zero; acc2[cg] = zero; }
  if (t < 128) mw[t >> 1][t & 1] = 0u;

  gld16(pAhi, &sm[0][0][ch]);
  gld16(pAlo, &sm[0][1][ch]);
  gld16(pBhi, &sm[0][2][ch]);
  gld16(pBlo, &sm[0][3][ch]);
  __syncthreads();

  for (int step = 0; step < NKSTEP; ++step) {
    int buf = step & 1;
    if (step < NKSTEP - 1) {
      int kb = (step + 1) * 32;
      gld16(pAhi + kb, &sm[buf ^ 1][0][ch]);
      gld16(pAlo + kb, &sm[buf ^ 1][1][ch]);
      gld16(pBhi + kb, &sm[buf ^ 1][2][ch]);
      gld16(pBlo + kb, &sm[buf ^ 1][3][ch]);
    }
    h8 ah = *reinterpret_cast<const h8*>(&sm[buf][0][aRead]);
    h8 al = *reinterpret_cast<const h8*>(&sm[buf][1][aRead]);
    #pragma unroll
    for (int cg = 0; cg < 4; ++cg) {
      int bRead = (cg * 16 + fr) * 32 + kq8;
      h8 bh = *reinterpret_cast<const h8*>(&sm[buf][2][bRead]);
      h8 bl = *reinterpret_cast<const h8*>(&sm[buf][3][bRead]);
      acc1[cg] = MFMA16(ah, bh, acc1[cg]);
      acc2[cg] = MFMA16(ah, bl, acc2[cg]);
      acc2[cg] = MFMA16(al, bh, acc2[cg]);
    }
    __syncthreads();
  }

  int rloc = wv * 16 + kg * 4;
  float nrv[4];
  #pragma unroll
  for (int i = 0; i < 4; ++i) {
    int r = r0 + rloc + i;
    nrv[i] = norms[NL + (r < NL ? r : NL - 1)];
  }
  #pragma unroll
  for (int cg = 0; cg < 4; ++cg) {
    int lloc = cg * 16 + fr;
    int l = l0 + lloc;
    float nlv = norms[l < NL ? l : NL - 1];
    #pragma unroll
    for (int i = 0; i < 4; ++i) {
      int r = r0 + rloc + i;
      float dot = acc1[cg][i] + acc2[cg][i] * (1.f / 2048.f);
      if (r < NL && l < NL && dot > 0.1f * nrv[i] * nlv)
        atomicOr(&mw[rloc + i][lloc >> 5], 1u << (lloc & 31));
    }
  }
  __syncthreads();
  if (t < 128) {
    int rr = t >> 1, w = t & 1;
    int rg = r0 + rr, wg = blockIdx.y * 2 + w;
    if (rg < NL && wg < WPR) mask[(size_t)rg * WPR + wg] = mw[rr][w];
  }
}

// ---------------------------------------------------------------- build neighbor lists from bitmask (once)
__global__ __launch_bounds__(64) void build_csr(const unsigned* __restrict__ mask,
                                                int* __restrict__ nbr, int* __restrict__ deg) {
  int r = blockIdx.x * 64 + threadIdx.x;
  if (r >= NL) return;
  const unsigned* mr = mask + (size_t)r * WPR;
  int* out = nbr + (size_t)r * MAXDEG;
  int cnt = 0;
  #pragma unroll 7
  for (int w = 0; w < WPR; ++w) {
    unsigned m = mr[w];
    while (m) {
      int bpos = __ffs(m) - 1;
      m &= m - 1;
      if (cnt < MAXDEG) out[cnt] = w * 32 + bpos;
      ++cnt;
    }
  }
  deg[r] = cnt < MAXDEG ? cnt : MAXDEG;
}

// ---------------------------------------------------------------- fused sparse bipartite attention (z in fp16)
__global__ __launch_bounds__(768) void bip_fused(const _Float16* __restrict__ zh, const float* __restrict__ el,
                                                 const float* __restrict__ er, const int* __restrict__ nbr,
                                                 const int* __restrict__ deg, const float* __restrict__ bias,
                                                 _Float16* __restrict__ ohhi,
                                                 int do_elu) {
  int r = blockIdx.x;
  int R = NL + r;
  int t = threadIdx.x;
  int dg = deg[r];
  __shared__ int nb_s[MAXDEG];
  __shared__ float wbuf[MAXDEG * NH];
  __shared__ float den_s[NH], wself_s[NH];
  if (t < dg) nb_s[t] = nbr[(size_t)r * MAXDEG + t];
  __syncthreads();
  if (t < dg * NH) {
    int j = t / NH, h2 = t - j * NH;
    wbuf[t] = el[(size_t)nb_s[j] * NH + h2];
  }
  __syncthreads();
  if (t < NH) {
    float er_r = er[(size_t)R * NH + t];
    float s = leaky(el[(size_t)R * NH + t] + er_r);
    float mx = s;
    for (int j = 0; j < dg; ++j) mx = fmaxf(mx, leaky(wbuf[j * NH + t] + er_r));
    float den = 0.f;
    for (int j = 0; j < dg; ++j) {
      float w = expf(leaky(wbuf[j * NH + t] + er_r) - mx);
      wbuf[j * NH + t] = w;
      den += w;
    }
    float ws = expf(s - mx);
    den_s[t] = den + ws;
    wself_s[t] = ws;
  }
  __syncthreads();
  int h2 = t >> 6;
  float acc = wself_s[h2] * (float)zh[(size_t)R * DD + t];
  for (int j = 0; j < dg; ++j)
    acc = fmaf(wbuf[j * NH + h2], (float)zh[(size_t)nb_s[j] * DD + t], acc);
  float o = acc / den_s[h2] + bias[t];
  if (do_elu) o = o > 0.f ? o : expm1f(o);
  ohhi[(size_t)R * DD + t] = (_Float16)o;
}

// ---------------------------------------------------------------- pool attention, (group, head) per block, 4 waves
__global__ __launch_bounds__(256) void pool_attn2(const _Float16* __restrict__ zh, const float* __restrict__ el,
                                                  const float* __restrict__ er, const float* __restrict__ bias,
                                                  _Float16* __restrict__ ohhi,
                                                  float* __restrict__ root_out, int do_elu) {
  int g = blockIdx.x, h = blockIdx.y;
  int base = g * 196;
  int t = threadIdx.x;
  int w = t >> 6, d = t & 63;
  __shared__ float wb[196];
  __shared__ float red[4];
  __shared__ float accP[4][64];
  float er0 = er[(size_t)base * NH + h];
  float lg = -INFINITY;
  if (t < 196) {
    lg = leaky(el[(size_t)(base + t) * NH + h] + er0);
    if (t == 0) lg += LOG2F_;
  }
  float m = lg;
  #pragma unroll
  for (int o = 32; o; o >>= 1) m = fmaxf(m, __shfl_xor(m, o));
  if ((t & 63) == 0) red[w] = m;
  __syncthreads();
  float mx = fmaxf(fmaxf(red[0], red[1]), fmaxf(red[2], red[3]));
  float wgt = (t < 196) ? expf(lg - mx) : 0.f;
  if (t < 196) wb[t] = wgt;
  float dn = wgt;
  #pragma unroll
  for (int o = 32; o; o >>= 1) dn += __shfl_xor(dn, o);
  __syncthreads();
  if ((t & 63) == 0) red[w] = dn;
  __syncthreads();
  float den = red[0] + red[1] + red[2] + red[3];
  float acc = 0.f;
  int p0 = w * 49;
  #pragma unroll 7
  for (int p = p0; p < p0 + 49; ++p)
    acc = fmaf(wb[p], (float)zh[(size_t)(base + p) * DD + h * DHD + d], acc);
  accP[w][d] = acc;
  __syncthreads();
  if (w == 0) {
    float o = (accP[0][d] + accP[1][d] + accP[2][d] + accP[3][d]) / den + bias[h * DHD + d];
    if (do_elu) o = o > 0.f ? o : expm1f(o);
    int c = h * DHD + d;
    ohhi[(size_t)base * DD + c] = (_Float16)o;
    root_out[(size_t)g * DD + c] = o;
  }
}

extern "C" void kernel_launch(void* const* d_in, const int* in_sizes, int n_in,
                              void* d_out, int out_size, void* d_ws, size_t ws_size,
                              hipStream_t stream) {
  const float* l_feat = (const float*)d_in[0];
  const float* r_feat = (const float*)d_in[1];
  const float* W      = (const float*)d_in[2];   // (4, 768, 768)
  const float* a_src  = (const float*)d_in[3];   // (4, 12, 64)
  const float* a_dst  = (const float*)d_in[4];
  const float* b      = (const float*)d_in[5];   // (4, 768)
  float* out = (float*)d_out;

  float* el    = (float*)d_ws;                   // NTOT*NH
  float* er    = el + (size_t)NTOT * NH;         // NTOT*NH
  float* norms = er + (size_t)NTOT * NH;         // NTOT
  float* hroot = norms + NTOT;                   // 16*DD scratch
  unsigned* mask = (unsigned*)(hroot + 16 * DD); // NL*WPR
  int* nbr = (int*)(mask + (size_t)NL * WPR);    // NL*MAXDEG
  int* deg = nbr + (size_t)NL * MAXDEG;          // NL
  _Float16* hhiA = (_Float16*)(deg + NL);        // NTOT*DD halves (ping)
  _Float16* hloA = hhiA + (size_t)NTOT * DD;     // layer-0 lo plane (mask only)
  _Float16* hhiB = hloA + (size_t)NTOT * DD;     // NTOT*DD halves (pong)
  _Float16* Wthi = hhiB + (size_t)NTOT * DD;     // 4*DD*DD halves
  _Float16* zh   = Wthi + (size_t)4 * DD * DD;   // NTOT*DD halves (fp16 z)

  _Float16* hhi[2] = {hhiA, hhiB};

  conv_init<<<NTOT, 192, 0, stream>>>(l_feat, r_feat, hhiA, hloA, norms);
  transp_W<<<dim3(24, 24, 4), 256, 0, stream>>>(W, Wthi);
  mask_mfma<<<dim3(25, 25), 256, 0, stream>>>(hhiA, hloA, norms, mask);
  build_csr<<<(NL + 63) / 64, 64, 0, stream>>>(mask, nbr, deg);

  // ---- 4 bipartite layers (ping-pong h planes: layer L reads L&1, writes (L+1)&1)
  for (int i = 0; i < 4; ++i) {
    const float* bi = b + (size_t)i * DD;
    int do_elu = (i < 3) ? 1 : 0;
    int ib = i & 1, ob = (i + 1) & 1;
    gemm_mfma<<<588, 256, 0, stream>>>(hhi[ib],
        Wthi + (size_t)i * DD * DD,
        a_src + (size_t)i * NH * DHD, a_dst + (size_t)i * NH * DHD,
        bi, zh, el, er, hhi[ob], do_elu, 0);
    bip_fused<<<NL, 768, 0, stream>>>(zh, el, er, nbr, deg, bi, hhi[ob], do_elu);
  }

  // ---- 4 pool layers
  for (int i = 0; i < 4; ++i) {
    const float* bi = b + (size_t)i * DD;
    int do_elu = (i < 3) ? 1 : 0;
    int L = 4 + i;
    int ib = L & 1, ob = (L + 1) & 1;
    gemm_mfma<<<588, 256, 0, stream>>>(hhi[ib],
        Wthi + (size_t)i * DD * DD,
        a_src + (size_t)i * NH * DHD, a_dst + (size_t)i * NH * DHD,
        bi, zh, el, er, hhi[ob], do_elu, 1);
    pool_attn2<<<dim3(16, NH), 256, 0, stream>>>(zh, el, er, bi, hhi[ob],
        (i == 3) ? out : hroot, do_elu);
  }
}